// Round 8
// baseline (277.764 us; speedup 1.0000x reference)
//
#include <hip/hip_runtime.h>
#include <math.h>

#define B_ 256
#define N_ 128
#define D_ 128
#define L_ 32
#define E_ 262144
#define PW_ 254          // bitmap words per graph = 8128/32
#define DCAP 96          // per-node neighbor capacity (max deg ~40 expected)

// workspace layout (u32 units)
#define NDEG_OFF 0               // 32768 u32 per-node degree counters
#define BM_OFF   32768           // 65024 u32 pair-target bitmap
#define KLS_OFF  97792           // 256 f32 per-graph KL sums
#define LP_OFF   98048           // 256 f32 per-graph log_prob sums
#define ADJ_OFF  98304           // 32768*96 u8 CSR neighbor lists (786432 u32)
#define Z_OFF    884736          // 32768*32 f32 latents
#define ZERO_WORDS 98304         // ndeg + bitmap + kls + logp

// ---------------------------------------------------------------------------
// Per-edge: CSR adjacency build (atomics over 32768 node counters) + bitmap.
__global__ __launch_bounds__(256) void k_build(
    const int* __restrict__ ei, unsigned* __restrict__ ndeg,
    unsigned char* __restrict__ adj, unsigned* __restrict__ bm)
{
    int e = blockIdx.x * 256 + threadIdx.x;
    int src = ei[e], dst = ei[E_ + e];
    unsigned s1 = atomicAdd(&ndeg[src], 1u);
    if (s1 < DCAP) adj[(size_t)src * DCAP + s1] = (unsigned char)(dst & 127);
    unsigned s2 = atomicAdd(&ndeg[dst], 1u);
    if (s2 < DCAP) adj[(size_t)dst * DCAP + s2] = (unsigned char)(src & 127);
    int li = src & 127, lj = dst & 127, g = src >> 7;
    int p = li * (255 - li) / 2 + (lj - li - 1);
    atomicOr(&bm[g * PW_ + (p >> 5)], 1u << (p & 31));
}

// ---------------------------------------------------------------------------
// Fused gather+encoder, wave-autonomous: block = 32 rows (4 waves x 8 rows),
// 1024 blocks, XCD-swizzled (graph = blockIdx&255). Each wave owns a private
// 8x132 LDS slab (XA, later H) -> gather/H transpose need no barriers.
// W1 staged in 8 double-buffered 16-row chunks; WB in 4 double-buffered
// 32-row chunks -> one barrier per chunk, loads prefetched a chunk ahead.
// LDS 33.3 KB -> 4 blocks/CU.
__global__ __launch_bounds__(256, 4) void k_encoder(
    const float* __restrict__ x, const unsigned* __restrict__ ndeg,
    const unsigned char* __restrict__ adj,
    const float* __restrict__ W1, const float* __restrict__ b1,
    const float* __restrict__ Wmu, const float* __restrict__ bmu,
    const float* __restrict__ Wls, const float* __restrict__ bls,
    const float* __restrict__ eps,
    float* __restrict__ z, float* __restrict__ kls)
{
    __shared__ float XAW[4][8 * 132];   // 16896 B, wave-private slabs
    __shared__ float Ws[2][2048];       // 16384 B, double-buffered W chunks
    int t = threadIdx.x;
    int g = blockIdx.x & 255;           // fixes XCD (g % 8)
    int quar = blockIdx.x >> 8;
    int row0 = g * 128 + quar * 32;
    int w = t >> 6, lane = t & 63;
    int rg = lane >> 5;                 // 0..1 (row half of slab)
    int cg = lane & 31;
    float* myA = XAW[w];
    int wrow0 = row0 + w * 8;

    // ---- issue W1 chunk-0 loads first (land during gather) ----
    float4 wp0 = ((const float4*)W1)[t];
    float4 wp1 = ((const float4*)W1)[t + 256];

    // ---- gather 8 rows into my slab: 2 passes x 4 rows, 16 lanes/row ----
    {
        int sub = lane >> 4;            // 0..3
        int fo = (lane & 15) * 8;
        #pragma unroll 2
        for (int p = 0; p < 2; ++p) {
            int lrow = p * 4 + sub;
            int gnode = wrow0 + lrow;
            const float* xr = x + (size_t)gnode * 128 + fo;
            float4 a0 = *(const float4*)xr;
            float4 a1 = *(const float4*)(xr + 4);
            int deg = (int)ndeg[gnode];
            if (deg > DCAP) deg = DCAP;
            const unsigned char* al = adj + (size_t)gnode * DCAP;
            const float* gx = x + (size_t)(gnode & ~127) * 128 + fo;
            int e = 0;
            for (; e + 4 <= deg; e += 4) {
                unsigned pk = *(const unsigned*)(al + e);
                const float* r0 = gx + (pk & 255u) * 128;
                const float* r1 = gx + ((pk >> 8) & 255u) * 128;
                const float* r2 = gx + ((pk >> 16) & 255u) * 128;
                const float* r3 = gx + (pk >> 24) * 128;
                float4 v00 = *(const float4*)r0, v01 = *(const float4*)(r0 + 4);
                float4 v10 = *(const float4*)r1, v11 = *(const float4*)(r1 + 4);
                float4 v20 = *(const float4*)r2, v21 = *(const float4*)(r2 + 4);
                float4 v30 = *(const float4*)r3, v31 = *(const float4*)(r3 + 4);
                a0.x += v00.x + v10.x + v20.x + v30.x;
                a0.y += v00.y + v10.y + v20.y + v30.y;
                a0.z += v00.z + v10.z + v20.z + v30.z;
                a0.w += v00.w + v10.w + v20.w + v30.w;
                a1.x += v01.x + v11.x + v21.x + v31.x;
                a1.y += v01.y + v11.y + v21.y + v31.y;
                a1.z += v01.z + v11.z + v21.z + v31.z;
                a1.w += v01.w + v11.w + v21.w + v31.w;
            }
            for (; e < deg; ++e) {
                const float* r = gx + (unsigned)al[e] * 128;
                float4 v0 = *(const float4*)r, v1 = *(const float4*)(r + 4);
                a0.x += v0.x; a0.y += v0.y; a0.z += v0.z; a0.w += v0.w;
                a1.x += v1.x; a1.y += v1.y; a1.z += v1.z; a1.w += v1.w;
            }
            *(float4*)(myA + lrow * 132 + fo) = a0;
            *(float4*)(myA + lrow * 132 + fo + 4) = a1;
        }
    }
    // commit W1 chunk 0
    ((float4*)Ws[0])[t] = wp0;
    ((float4*)Ws[0])[t + 256] = wp1;
    __syncthreads();

    // ---- GEMM1: h-pre = XA @ W1, 8 chunks of 16 k-rows, double-buffered ----
    float acc[4][4];
    #pragma unroll
    for (int i = 0; i < 4; ++i)
        #pragma unroll
        for (int j = 0; j < 4; ++j) acc[i][j] = 0.f;

    for (int c = 0; c < 8; ++c) {
        if (c < 7) {                    // prefetch chunk c+1
            wp0 = ((const float4*)(W1 + (c + 1) * 2048))[t];
            wp1 = ((const float4*)(W1 + (c + 1) * 2048))[t + 256];
        }
        const float* WsC = Ws[c & 1];
        #pragma unroll
        for (int k = 0; k < 16; k += 4) {
            float4 av[4], wv[4];
            #pragma unroll
            for (int i = 0; i < 4; ++i)
                av[i] = *(const float4*)(myA + (4 * rg + i) * 132 + c * 16 + k);
            #pragma unroll
            for (int dk = 0; dk < 4; ++dk)
                wv[dk] = *(const float4*)(WsC + (k + dk) * 128 + 4 * cg);
            #pragma unroll
            for (int i = 0; i < 4; ++i) {
                acc[i][0] += av[i].x * wv[0].x + av[i].y * wv[1].x + av[i].z * wv[2].x + av[i].w * wv[3].x;
                acc[i][1] += av[i].x * wv[0].y + av[i].y * wv[1].y + av[i].z * wv[2].y + av[i].w * wv[3].y;
                acc[i][2] += av[i].x * wv[0].z + av[i].y * wv[1].z + av[i].z * wv[2].z + av[i].w * wv[3].z;
                acc[i][3] += av[i].x * wv[0].w + av[i].y * wv[1].w + av[i].z * wv[2].w + av[i].w * wv[3].w;
            }
        }
        if (c < 7) {
            float* WsN = Ws[(c + 1) & 1];
            ((float4*)WsN)[t] = wp0;
            ((float4*)WsN)[t + 256] = wp1;
            __syncthreads();
        }
    }
    // no barrier needed: H writes are wave-local, WB q0 goes to Ws[0]
    // whose last readers (chunk 6) are behind the chunk-6 barrier.

    // ---- relu + b1 -> H in my slab (wave-local, DS ops are in-order) ----
    {
        float4 bb = *(const float4*)(b1 + 4 * cg);
        #pragma unroll
        for (int i = 0; i < 4; ++i) {
            float4 h;
            h.x = fmaxf(acc[i][0] + bb.x, 0.f);
            h.y = fmaxf(acc[i][1] + bb.y, 0.f);
            h.z = fmaxf(acc[i][2] + bb.z, 0.f);
            h.w = fmaxf(acc[i][3] + bb.w, 0.f);
            *(float4*)(myA + (4 * rg + i) * 132 + 4 * cg) = h;
        }
    }

    // ---- GEMM2: [mu|ls] = H @ WB, 4 chunks of 32 k-rows, double-buffered --
    // WB chunk q: rows [32q,32q+32) of [Wmu|Wls] -> Ws as [32][64]
    {
        int f0 = t, f1 = t + 256;       // float4 indices within chunk (512 total)
        int r0_ = f0 >> 4, c0_ = (f0 & 15) << 2;
        int r1_ = f1 >> 4, c1_ = (f1 & 15) << 2;
        wp0 = (c0_ < 32) ? *(const float4*)(Wmu + r0_ * 32 + c0_)
                         : *(const float4*)(Wls + r0_ * 32 + c0_ - 32);
        wp1 = (c1_ < 32) ? *(const float4*)(Wmu + r1_ * 32 + c1_)
                         : *(const float4*)(Wls + r1_ * 32 + c1_ - 32);
        ((float4*)Ws[0])[f0] = wp0;
        ((float4*)Ws[0])[f1] = wp1;
    }
    __syncthreads();

    float a2[4][2];
    #pragma unroll
    for (int i = 0; i < 4; ++i) { a2[i][0] = 0.f; a2[i][1] = 0.f; }

    for (int q = 0; q < 4; ++q) {
        if (q < 3) {
            int f0 = t, f1 = t + 256;
            int r0_ = (q + 1) * 32 + (f0 >> 4), c0_ = (f0 & 15) << 2;
            int r1_ = (q + 1) * 32 + (f1 >> 4), c1_ = (f1 & 15) << 2;
            wp0 = (c0_ < 32) ? *(const float4*)(Wmu + r0_ * 32 + c0_)
                             : *(const float4*)(Wls + r0_ * 32 + c0_ - 32);
            wp1 = (c1_ < 32) ? *(const float4*)(Wmu + r1_ * 32 + c1_)
                             : *(const float4*)(Wls + r1_ * 32 + c1_ - 32);
        }
        const float* WsC = Ws[q & 1];
        #pragma unroll
        for (int k = 0; k < 32; k += 4) {
            float4 av[4];
            float2 wv[4];
            #pragma unroll
            for (int i = 0; i < 4; ++i)
                av[i] = *(const float4*)(myA + (4 * rg + i) * 132 + q * 32 + k);
            #pragma unroll
            for (int dk = 0; dk < 4; ++dk)
                wv[dk] = *(const float2*)(WsC + (k + dk) * 64 + 2 * cg);
            #pragma unroll
            for (int i = 0; i < 4; ++i) {
                a2[i][0] += av[i].x * wv[0].x + av[i].y * wv[1].x + av[i].z * wv[2].x + av[i].w * wv[3].x;
                a2[i][1] += av[i].x * wv[0].y + av[i].y * wv[1].y + av[i].z * wv[2].y + av[i].w * wv[3].y;
            }
        }
        if (q < 3) {
            float* WsN = Ws[(q + 1) & 1];
            ((float4*)WsN)[t] = wp0;
            ((float4*)WsN)[t + 256] = wp1;
            __syncthreads();
        }
    }
    {
        float2 bv = (cg < 16) ? ((const float2*)bmu)[cg] : ((const float2*)bls)[cg - 16];
        #pragma unroll
        for (int i = 0; i < 4; ++i) { a2[i][0] += bv.x; a2[i][1] += bv.y; }
    }

    // exchange mu<->ls with partner lane (cg ^ 16)
    float o2[4][2];
    #pragma unroll
    for (int i = 0; i < 4; ++i) {
        o2[i][0] = __shfl_xor(a2[i][0], 16);
        o2[i][1] = __shfl_xor(a2[i][1], 16);
    }

    // ---- z = mu + exp(ls)*eps, KL; wave shfl-reduce; 1 atomic per wave ----
    float klsum = 0.f;
    if (cg < 16) {
        int lo = cg;
        #pragma unroll
        for (int i = 0; i < 4; ++i) {
            int rowg = wrow0 + 4 * rg + i;
            float mu0 = a2[i][0], mu1 = a2[i][1];
            float ls0 = o2[i][0], ls1 = o2[i][1];
            float2 ev = *(const float2*)(eps + (size_t)rowg * 32 + 2 * lo);
            float s0 = __expf(ls0), s1 = __expf(ls1);
            float2 zv = make_float2(mu0 + s0 * ev.x, mu1 + s1 * ev.y);
            *(float2*)(z + (size_t)rowg * 32 + 2 * lo) = zv;
            klsum += s0 * s0 + mu0 * mu0 - 1.f - 2.f * ls0
                   + s1 * s1 + mu1 * mu1 - 1.f - 2.f * ls1;
        }
    }
    #pragma unroll
    for (int off = 32; off > 0; off >>= 1) klsum += __shfl_xor(klsum, off);
    if (lane == 0) atomicAdd(&kls[g], 0.5f * klsum);
}

// ---------------------------------------------------------------------------
// Decoder: 4 blocks per graph (i-quarters), XCD-swizzled; shfl-reduce +
// one atomic per wave; fast-math softplus.
__global__ __launch_bounds__(256) void k_decoder(
    const float* __restrict__ z, const unsigned* __restrict__ bitmap,
    float* __restrict__ logp)
{
    __shared__ float zT[32 * 132];
    __shared__ unsigned bm[PW_];
    int b = blockIdx.x & 255, quar = blockIdx.x >> 8, t = threadIdx.x;

    #pragma unroll
    for (int i = 0; i < 16; ++i) {
        int c = t + i * 256;
        int n = c >> 5, l = c & 31;
        zT[l * 132 + n] = z[((size_t)b * N_ + n) * L_ + l];
    }
    if (t < PW_) bm[t] = bitmap[b * PW_ + t];
    __syncthreads();

    int i0 = quar * 32 + ((t >> 5) << 2);
    int j0 = (t & 31) << 2;
    float g[4][4];
    #pragma unroll
    for (int a = 0; a < 4; ++a)
        #pragma unroll
        for (int c = 0; c < 4; ++c) g[a][c] = 0.f;

    #pragma unroll 4
    for (int l = 0; l < 32; ++l) {
        float4 a0 = *(const float4*)(zT + l * 132 + i0);
        float4 b0 = *(const float4*)(zT + l * 132 + j0);
        float za[4] = {a0.x, a0.y, a0.z, a0.w};
        float zb[4] = {b0.x, b0.y, b0.z, b0.w};
        #pragma unroll
        for (int a = 0; a < 4; ++a)
            #pragma unroll
            for (int c = 0; c < 4; ++c) g[a][c] += za[a] * zb[c];
    }

    float sum = 0.f;
    #pragma unroll
    for (int a = 0; a < 4; ++a) {
        int i = i0 + a;
        #pragma unroll
        for (int c = 0; c < 4; ++c) {
            int j = j0 + c;
            if (j > i) {
                float lg = g[a][c];
                int p = i * (255 - i) / 2 + (j - i - 1);
                unsigned bit = (bm[p >> 5] >> (p & 31)) & 1u;
                float sp = __logf(1.f + __expf(-fabsf(lg))) + fmaxf(lg, 0.f);
                sum += bit ? (lg - sp) : (-sp);
            }
        }
    }
    #pragma unroll
    for (int off = 32; off > 0; off >>= 1) sum += __shfl_xor(sum, off);
    if ((t & 63) == 0) atomicAdd(&logp[b], sum);
}

// ---------------------------------------------------------------------------
__global__ __launch_bounds__(256) void k_finalize(
    const float* __restrict__ kls, const float* __restrict__ logp,
    float* __restrict__ out)
{
    __shared__ float RED[256];
    int t = threadIdx.x;
    RED[t] = logp[t] - kls[t];
    __syncthreads();
    for (int s = 128; s > 0; s >>= 1) {
        if (t < s) RED[t] += RED[t + s];
        __syncthreads();
    }
    if (t == 0) out[0] = -RED[0] * (1.0f / 256.0f);
}

// ---------------------------------------------------------------------------
extern "C" void kernel_launch(void* const* d_in, const int* in_sizes, int n_in,
                              void* d_out, int out_size, void* d_ws, size_t ws_size,
                              hipStream_t stream) {
    const float* x   = (const float*)d_in[0];
    const int*   ei  = (const int*)d_in[1];
    // d_in[2] = batch (unused; block-contiguous layout known)
    const float* eps = (const float*)d_in[3];
    const float* W1  = (const float*)d_in[4];
    const float* b1  = (const float*)d_in[5];
    const float* Wmu = (const float*)d_in[6];
    const float* bmu = (const float*)d_in[7];
    const float* Wls = (const float*)d_in[8];
    const float* bls = (const float*)d_in[9];

    unsigned* wsw = (unsigned*)d_ws;
    unsigned*      ndeg = wsw + NDEG_OFF;
    unsigned*      bm   = wsw + BM_OFF;
    float*         kls  = (float*)(wsw + KLS_OFF);
    float*         logp = (float*)(wsw + LP_OFF);
    unsigned char* adj  = (unsigned char*)(wsw + ADJ_OFF);
    float*         z    = (float*)(wsw + Z_OFF);

    hipMemsetAsync(d_ws, 0, ZERO_WORDS * sizeof(unsigned), stream);

    k_build   <<<E_ / 256, 256, 0, stream>>>(ei, ndeg, adj, bm);
    k_encoder <<<1024, 256, 0, stream>>>(x, ndeg, adj, W1, b1, Wmu, bmu,
                                         Wls, bls, eps, z, kls);
    k_decoder <<<4 * B_, 256, 0, stream>>>(z, bm, logp);
    k_finalize<<<1, 256, 0, stream>>>(kls, logp, (float*)d_out);
}

// Round 9
// 177.482 us; speedup vs baseline: 1.5650x; 1.5650x over previous
//
#include <hip/hip_runtime.h>
#include <math.h>

#define B_ 256
#define N_ 128
#define D_ 128
#define L_ 32
#define E_ 262144
#define PW_ 254          // bitmap words per graph = 8128/32
#define DCAP 96          // per-node neighbor capacity (max deg ~40 expected)

// workspace layout (u32 units)
#define NDEG_OFF 0               // 32768 u32 per-node degree counters
#define BM_OFF   32768           // 65024 u32 pair-target bitmap
#define KLS_OFF  97792           // 256 f32 per-graph KL sums
#define LP_OFF   98048           // 256 f32 per-graph log_prob sums
#define ADJ_OFF  98304           // 32768*96 u8 CSR neighbor lists (786432 u32)
#define Z_OFF    884736          // 32768*32 f32 latents
#define ZERO_WORDS 98304         // ndeg + bitmap + kls + logp

// ---------------------------------------------------------------------------
// Per-edge: CSR adjacency build (atomics over 32768 node counters) + bitmap.
__global__ __launch_bounds__(256) void k_build(
    const int* __restrict__ ei, unsigned* __restrict__ ndeg,
    unsigned char* __restrict__ adj, unsigned* __restrict__ bm)
{
    int e = blockIdx.x * 256 + threadIdx.x;
    int src = ei[e], dst = ei[E_ + e];
    unsigned s1 = atomicAdd(&ndeg[src], 1u);
    if (s1 < DCAP) adj[(size_t)src * DCAP + s1] = (unsigned char)(dst & 127);
    unsigned s2 = atomicAdd(&ndeg[dst], 1u);
    if (s2 < DCAP) adj[(size_t)dst * DCAP + s2] = (unsigned char)(src & 127);
    int li = src & 127, lj = dst & 127, g = src >> 7;
    int p = li * (255 - li) / 2 + (lj - li - 1);
    atomicOr(&bm[g * PW_ + (p >> 5)], 1u << (p & 31));
}

// ---------------------------------------------------------------------------
// Fused gather+encoder (round-7 proven structure): block = 32 rows,
// 1024 blocks, XCD-swizzled (graph = blockIdx&255 — 256≡0 mod 8 keeps all
// 4 quarters of a graph on one XCD; FETCH measured ~19 MB). Direct
// global->LDS staging per W chunk (no register-held prefetch: round 8
// showed that spills to scratch at this occupancy). ~33 KB LDS, 4 blk/CU.
__global__ __launch_bounds__(256, 4) void k_encoder(
    const float* __restrict__ x, const unsigned* __restrict__ ndeg,
    const unsigned char* __restrict__ adj,
    const float* __restrict__ W1, const float* __restrict__ b1,
    const float* __restrict__ Wmu, const float* __restrict__ bmu,
    const float* __restrict__ Wls, const float* __restrict__ bls,
    const float* __restrict__ eps,
    float* __restrict__ z, float* __restrict__ kls)
{
    __shared__ float XAs[32 * 132];   // 16896 B; reused as HS after GEMM1
    __shared__ float Ws[4096];        // 16384 B; W1 k-quarter / WB k-half
    int t = threadIdx.x;
    int g = blockIdx.x & 255;         // graph (fixes XCD: g % 8)
    int quar = blockIdx.x >> 8;       // 0..3
    int row0 = g * 128 + quar * 32;
    int rg = t >> 5;                  // 0..7
    int cg = t & 31;                  // 0..31
    int lane = t & 63;

    // ---- phase G: gather 32 XA rows; 2 passes x 16 nodes, 16 thr/node ----
    {
        int nidx = t >> 4;            // 0..15
        int fo = (t & 15) * 8;        // float offset 0..120
        for (int p = 0; p < 2; ++p) {
            int lrow = p * 16 + nidx;
            int gnode = row0 + lrow;
            const float* xr = x + (size_t)gnode * 128 + fo;
            float4 a0 = *(const float4*)xr;
            float4 a1 = *(const float4*)(xr + 4);
            int deg = (int)ndeg[gnode];
            if (deg > DCAP) deg = DCAP;
            const unsigned char* al = adj + (size_t)gnode * DCAP;
            const float* gx = x + (size_t)(gnode & ~127) * 128 + fo;
            int e = 0;
            for (; e + 4 <= deg; e += 4) {
                unsigned pk = *(const unsigned*)(al + e);
                const float* r0 = gx + (pk & 255u) * 128;
                const float* r1 = gx + ((pk >> 8) & 255u) * 128;
                const float* r2 = gx + ((pk >> 16) & 255u) * 128;
                const float* r3 = gx + (pk >> 24) * 128;
                float4 v00 = *(const float4*)r0, v01 = *(const float4*)(r0 + 4);
                float4 v10 = *(const float4*)r1, v11 = *(const float4*)(r1 + 4);
                float4 v20 = *(const float4*)r2, v21 = *(const float4*)(r2 + 4);
                float4 v30 = *(const float4*)r3, v31 = *(const float4*)(r3 + 4);
                a0.x += v00.x + v10.x + v20.x + v30.x;
                a0.y += v00.y + v10.y + v20.y + v30.y;
                a0.z += v00.z + v10.z + v20.z + v30.z;
                a0.w += v00.w + v10.w + v20.w + v30.w;
                a1.x += v01.x + v11.x + v21.x + v31.x;
                a1.y += v01.y + v11.y + v21.y + v31.y;
                a1.z += v01.z + v11.z + v21.z + v31.z;
                a1.w += v01.w + v11.w + v21.w + v31.w;
            }
            for (; e < deg; ++e) {
                const float* r = gx + (unsigned)al[e] * 128;
                float4 v0 = *(const float4*)r, v1 = *(const float4*)(r + 4);
                a0.x += v0.x; a0.y += v0.y; a0.z += v0.z; a0.w += v0.w;
                a1.x += v1.x; a1.y += v1.y; a1.z += v1.z; a1.w += v1.w;
            }
            *(float4*)(XAs + lrow * 132 + fo) = a0;
            *(float4*)(XAs + lrow * 132 + fo + 4) = a1;
        }
    }
    __syncthreads();

    // ---- phase 1: h = relu(XA @ W1 + b1), W1 in 4 K-quarters ----
    float acc[4][4];
    #pragma unroll
    for (int i = 0; i < 4; ++i)
        #pragma unroll
        for (int j = 0; j < 4; ++j) acc[i][j] = 0.f;

    for (int kq = 0; kq < 4; ++kq) {
        if (kq) __syncthreads();
        #pragma unroll
        for (int i = 0; i < 4; ++i) {
            int c = t + i * 256;      // 1024 float4 = 32x128 W1 rows
            ((float4*)Ws)[c] = ((const float4*)(W1 + kq * 4096))[c];
        }
        __syncthreads();
        #pragma unroll 2
        for (int k = 0; k < 32; k += 4) {
            float4 av[4], wv[4];
            #pragma unroll
            for (int i = 0; i < 4; ++i)
                av[i] = *(const float4*)(XAs + (4 * rg + i) * 132 + kq * 32 + k);
            #pragma unroll
            for (int dk = 0; dk < 4; ++dk)
                wv[dk] = *(const float4*)(Ws + (k + dk) * 128 + 4 * cg);
            #pragma unroll
            for (int i = 0; i < 4; ++i) {
                acc[i][0] += av[i].x * wv[0].x + av[i].y * wv[1].x + av[i].z * wv[2].x + av[i].w * wv[3].x;
                acc[i][1] += av[i].x * wv[0].y + av[i].y * wv[1].y + av[i].z * wv[2].y + av[i].w * wv[3].y;
                acc[i][2] += av[i].x * wv[0].z + av[i].y * wv[1].z + av[i].z * wv[2].z + av[i].w * wv[3].z;
                acc[i][3] += av[i].x * wv[0].w + av[i].y * wv[1].w + av[i].z * wv[2].w + av[i].w * wv[3].w;
            }
        }
    }
    __syncthreads();                  // all XAs reads done -> reuse as HS

    {
        float4 bb = *(const float4*)(b1 + 4 * cg);
        #pragma unroll
        for (int i = 0; i < 4; ++i) {
            float4 h;
            h.x = fmaxf(acc[i][0] + bb.x, 0.f);
            h.y = fmaxf(acc[i][1] + bb.y, 0.f);
            h.z = fmaxf(acc[i][2] + bb.z, 0.f);
            h.w = fmaxf(acc[i][3] + bb.w, 0.f);
            *(float4*)(XAs + (4 * rg + i) * 132 + 4 * cg) = h;
        }
    }

    // ---- phase 2: [mu|ls] = h @ WB + bias, WB in 2 K-halves ----
    float a3[4][2];
    #pragma unroll
    for (int i = 0; i < 4; ++i) { a3[i][0] = 0.f; a3[i][1] = 0.f; }

    for (int kh = 0; kh < 2; ++kh) {
        __syncthreads();              // HS visible (kh=0) / prior Ws reads done
        #pragma unroll
        for (int i = 0; i < 4; ++i) {
            int c = t + i * 256;      // 1024 float4 = 64 rows x 64 cols
            int row = c >> 4, col4 = (c & 15) << 2;
            int rowg = kh * 64 + row;
            float4 v = (col4 < 32) ? *(const float4*)(Wmu + rowg * 32 + col4)
                                   : *(const float4*)(Wls + rowg * 32 + col4 - 32);
            *(float4*)(Ws + row * 64 + col4) = v;
        }
        __syncthreads();
        #pragma unroll 2
        for (int k = 0; k < 64; k += 4) {
            float4 av[4];
            float2 wv[4];
            #pragma unroll
            for (int i = 0; i < 4; ++i)
                av[i] = *(const float4*)(XAs + (4 * rg + i) * 132 + kh * 64 + k);
            #pragma unroll
            for (int dk = 0; dk < 4; ++dk)
                wv[dk] = *(const float2*)(Ws + (k + dk) * 64 + 2 * cg);
            #pragma unroll
            for (int i = 0; i < 4; ++i) {
                a3[i][0] += av[i].x * wv[0].x + av[i].y * wv[1].x + av[i].z * wv[2].x + av[i].w * wv[3].x;
                a3[i][1] += av[i].x * wv[0].y + av[i].y * wv[1].y + av[i].z * wv[2].y + av[i].w * wv[3].y;
            }
        }
    }
    {
        float2 bv = (cg < 16) ? *(const float2*)(bmu + 2 * cg)
                              : *(const float2*)(bls + 2 * cg - 32);
        #pragma unroll
        for (int i = 0; i < 4; ++i) { a3[i][0] += bv.x; a3[i][1] += bv.y; }
    }

    // exchange mu<->ls with partner lane (cg ^ 16)
    float o3[4][2];
    #pragma unroll
    for (int i = 0; i < 4; ++i) {
        o3[i][0] = __shfl_xor(a3[i][0], 16);
        o3[i][1] = __shfl_xor(a3[i][1], 16);
    }

    // ---- phase 3: z = mu + exp(ls)*eps, KL; wave shfl-reduce, 1 atomic ----
    float klsum = 0.f;
    if (cg < 16) {                    // this lane holds mu; partner held ls
        int lo = cg;
        #pragma unroll
        for (int i = 0; i < 4; ++i) {
            int rowg = row0 + 4 * rg + i;
            float mu0 = a3[i][0], mu1 = a3[i][1];
            float ls0 = o3[i][0], ls1 = o3[i][1];
            float2 ev = *(const float2*)(eps + (size_t)rowg * 32 + 2 * lo);
            float s0 = __expf(ls0), s1 = __expf(ls1);
            float2 zv = make_float2(mu0 + s0 * ev.x, mu1 + s1 * ev.y);
            *(float2*)(z + (size_t)rowg * 32 + 2 * lo) = zv;
            klsum += s0 * s0 + mu0 * mu0 - 1.f - 2.f * ls0
                   + s1 * s1 + mu1 * mu1 - 1.f - 2.f * ls1;
        }
    }
    #pragma unroll
    for (int off = 32; off > 0; off >>= 1) klsum += __shfl_xor(klsum, off);
    if (lane == 0) atomicAdd(&kls[g], 0.5f * klsum);
}

// ---------------------------------------------------------------------------
// Decoder: 4 blocks per graph (i-quarters), XCD-swizzled; shfl-reduce +
// one atomic per wave; fast-math softplus.
__global__ __launch_bounds__(256) void k_decoder(
    const float* __restrict__ z, const unsigned* __restrict__ bitmap,
    float* __restrict__ logp)
{
    __shared__ float zT[32 * 132];
    __shared__ unsigned bm[PW_];
    int b = blockIdx.x & 255, quar = blockIdx.x >> 8, t = threadIdx.x;

    #pragma unroll
    for (int i = 0; i < 16; ++i) {
        int c = t + i * 256;
        int n = c >> 5, l = c & 31;
        zT[l * 132 + n] = z[((size_t)b * N_ + n) * L_ + l];
    }
    if (t < PW_) bm[t] = bitmap[b * PW_ + t];
    __syncthreads();

    int i0 = quar * 32 + ((t >> 5) << 2);
    int j0 = (t & 31) << 2;
    float g[4][4];
    #pragma unroll
    for (int a = 0; a < 4; ++a)
        #pragma unroll
        for (int c = 0; c < 4; ++c) g[a][c] = 0.f;

    #pragma unroll 4
    for (int l = 0; l < 32; ++l) {
        float4 a0 = *(const float4*)(zT + l * 132 + i0);
        float4 b0 = *(const float4*)(zT + l * 132 + j0);
        float za[4] = {a0.x, a0.y, a0.z, a0.w};
        float zb[4] = {b0.x, b0.y, b0.z, b0.w};
        #pragma unroll
        for (int a = 0; a < 4; ++a)
            #pragma unroll
            for (int c = 0; c < 4; ++c) g[a][c] += za[a] * zb[c];
    }

    float sum = 0.f;
    #pragma unroll
    for (int a = 0; a < 4; ++a) {
        int i = i0 + a;
        #pragma unroll
        for (int c = 0; c < 4; ++c) {
            int j = j0 + c;
            if (j > i) {
                float lg = g[a][c];
                int p = i * (255 - i) / 2 + (j - i - 1);
                unsigned bit = (bm[p >> 5] >> (p & 31)) & 1u;
                float sp = __logf(1.f + __expf(-fabsf(lg))) + fmaxf(lg, 0.f);
                sum += bit ? (lg - sp) : (-sp);
            }
        }
    }
    #pragma unroll
    for (int off = 32; off > 0; off >>= 1) sum += __shfl_xor(sum, off);
    if ((t & 63) == 0) atomicAdd(&logp[b], sum);
}

// ---------------------------------------------------------------------------
__global__ __launch_bounds__(256) void k_finalize(
    const float* __restrict__ kls, const float* __restrict__ logp,
    float* __restrict__ out)
{
    __shared__ float RED[256];
    int t = threadIdx.x;
    RED[t] = logp[t] - kls[t];
    __syncthreads();
    for (int s = 128; s > 0; s >>= 1) {
        if (t < s) RED[t] += RED[t + s];
        __syncthreads();
    }
    if (t == 0) out[0] = -RED[0] * (1.0f / 256.0f);
}

// ---------------------------------------------------------------------------
extern "C" void kernel_launch(void* const* d_in, const int* in_sizes, int n_in,
                              void* d_out, int out_size, void* d_ws, size_t ws_size,
                              hipStream_t stream) {
    const float* x   = (const float*)d_in[0];
    const int*   ei  = (const int*)d_in[1];
    // d_in[2] = batch (unused; block-contiguous layout known)
    const float* eps = (const float*)d_in[3];
    const float* W1  = (const float*)d_in[4];
    const float* b1  = (const float*)d_in[5];
    const float* Wmu = (const float*)d_in[6];
    const float* bmu = (const float*)d_in[7];
    const float* Wls = (const float*)d_in[8];
    const float* bls = (const float*)d_in[9];

    unsigned* wsw = (unsigned*)d_ws;
    unsigned*      ndeg = wsw + NDEG_OFF;
    unsigned*      bm   = wsw + BM_OFF;
    float*         kls  = (float*)(wsw + KLS_OFF);
    float*         logp = (float*)(wsw + LP_OFF);
    unsigned char* adj  = (unsigned char*)(wsw + ADJ_OFF);
    float*         z    = (float*)(wsw + Z_OFF);

    hipMemsetAsync(d_ws, 0, ZERO_WORDS * sizeof(unsigned), stream);

    k_build   <<<E_ / 256, 256, 0, stream>>>(ei, ndeg, adj, bm);
    k_encoder <<<1024, 256, 0, stream>>>(x, ndeg, adj, W1, b1, Wmu, bmu,
                                         Wls, bls, eps, z, kls);
    k_decoder <<<4 * B_, 256, 0, stream>>>(z, bm, logp);
    k_finalize<<<1, 256, 0, stream>>>(kls, logp, (float*)d_out);
}